// Round 2
// baseline (1964.817 us; speedup 1.0000x reference)
//
#include <hip/hip_runtime.h>
#include <hip/hip_bf16.h>
#include <math.h>

// Problem dims
#define TSTEPS 128
#define BATCH  64
#define EMBD   300
#define HID    256

// ---------------------------------------------------------------------------
// Kernel 1: gx[m][n] = sum_k emb[tok(m)][k] * W_ih[n][k] + b_ih[n] + b_hh[n]
//   M = 2*8192 rows (seq-major: seq0 rows 0..8191 = t*64+b), N = 1024, K = 300
//   fp32 vector GEMM, tile 128x64, BK=60, 256 threads, 8x4 micro-tile.
// ---------------------------------------------------------------------------
#define BM 128
#define BN 64
#define BK 60

__global__ __launch_bounds__(256) void gx_gemm_kernel(
    const int* __restrict__ s1, const int* __restrict__ s2,
    const float* __restrict__ emb, const float* __restrict__ Wih,
    const float* __restrict__ bih, const float* __restrict__ bhh,
    float* __restrict__ gx)
{
    __shared__ __align__(16) float As[BK][BM + 4];  // [k][m], stride 132 (528B, 16B-aligned)
    __shared__ __align__(16) float Bs[BK][BN + 4];  // [k][n], stride 68
    __shared__ int tokS[BM];

    const int tid = threadIdx.x;
    const int bm  = blockIdx.x & 127;   // 128 M-tiles
    const int bn  = blockIdx.x >> 7;    // 16 N-tiles
    const int m0  = bm * BM;
    const int n0  = bn * BN;

    const int* __restrict__ s = (m0 < 8192) ? s1 : s2;
    const int r0 = m0 & 8191;

    if (tid < BM) tokS[tid] = s[r0 + tid];

    const int tx = tid & 15;    // N micro (4 cols)
    const int ty = tid >> 4;    // M micro (8 rows)

    float4 bias;
    {
        const float4 b1 = *(const float4*)(bih + n0 + tx * 4);
        const float4 b2 = *(const float4*)(bhh + n0 + tx * 4);
        bias = make_float4(b1.x + b2.x, b1.y + b2.y, b1.z + b2.z, b1.w + b2.w);
    }

    float acc[8][4];
#pragma unroll
    for (int i = 0; i < 8; ++i) { acc[i][0] = 0.f; acc[i][1] = 0.f; acc[i][2] = 0.f; acc[i][3] = 0.f; }

    __syncthreads();   // tokS visible

    for (int kk = 0; kk < 5; ++kk) {
        const int k0 = kk * BK;
        // A: 128 rows x 60 k. flat-major over k within a row -> coalesced 240B runs.
#pragma unroll
        for (int l = 0; l < 30; ++l) {
            int flat = tid + l * 256;
            int m = flat / 60, k = flat - m * 60;
            As[k][m] = emb[(size_t)tokS[m] * EMBD + k0 + k];
        }
        // B: 64 rows x 60 k.
#pragma unroll
        for (int l = 0; l < 15; ++l) {
            int flat = tid + l * 256;
            int n = flat / 60, k = flat - n * 60;
            Bs[k][n] = Wih[(size_t)(n0 + n) * EMBD + k0 + k];
        }
        __syncthreads();

#pragma unroll 6
        for (int k = 0; k < BK; ++k) {
            const float4 a0 = *(const float4*)&As[k][ty * 8];
            const float4 a1 = *(const float4*)&As[k][ty * 8 + 4];
            const float4 b4 = *(const float4*)&Bs[k][tx * 4];
            const float av[8] = {a0.x, a0.y, a0.z, a0.w, a1.x, a1.y, a1.z, a1.w};
            const float bv[4] = {b4.x, b4.y, b4.z, b4.w};
#pragma unroll
            for (int i = 0; i < 8; ++i)
#pragma unroll
                for (int j = 0; j < 4; ++j)
                    acc[i][j] = fmaf(av[i], bv[j], acc[i][j]);
        }
        __syncthreads();
    }

    // epilogue: add bias, store coalesced float4
#pragma unroll
    for (int i = 0; i < 8; ++i) {
        const int m = m0 + ty * 8 + i;
        float4 v = make_float4(acc[i][0] + bias.x, acc[i][1] + bias.y,
                               acc[i][2] + bias.z, acc[i][3] + bias.w);
        *(float4*)(gx + (size_t)m * 1024 + n0 + tx * 4) = v;
    }
}

// ---------------------------------------------------------------------------
// DPP 16-lane sum (register-only butterfly: xor15, xor7, xor2, xor1 — spans GF(2)^4).
// All lanes end with the full 16-lane sum.
// ---------------------------------------------------------------------------
template <int CTRL>
__device__ __forceinline__ float dpp_fold(float v) {
    int x = __builtin_amdgcn_update_dpp(0, __float_as_int(v), CTRL, 0xF, 0xF, true);
    return v + __int_as_float(x);
}
__device__ __forceinline__ float red16(float v) {
    v = dpp_fold<0x140>(v);  // row_mirror (i -> 15-i = i^15)
    v = dpp_fold<0x141>(v);  // row_half_mirror (i -> i^7)
    v = dpp_fold<0x4E>(v);   // quad_perm [2,3,0,1] (xor 2)
    v = dpp_fold<0xB1>(v);   // quad_perm [1,0,3,2] (xor 1)
    return v;
}
__device__ __forceinline__ float sigmoidf_(float x) { return 1.0f / (1.0f + expf(-x)); }

// ---------------------------------------------------------------------------
// Kernel 2: recurrence. 256 blocks x 1024 threads.
//   group b = blockIdx%64 (batch row; both sequences), sub = blockIdx/64 (unit quarter).
//   (%64 keeps a group's 4 blocks on one XCD under round-robin placement — perf only;
//    correctness uses agent-scope atomics.)
//   Thread = (unit uL = tid>>4, kseg ks = tid&15). Owns all 4 gate rows of one unit
//   over 16 k -> 16 float4 weights in VGPRs (>=64 VGPR => hard 1 block/CU => all
//   256 blocks co-resident => spin barrier is safe without cooperative launch).
// ---------------------------------------------------------------------------
__global__ __launch_bounds__(1024) void lstm_rec_kernel(
    const float* __restrict__ gx,    // [2][8192][1024]
    const float* __restrict__ Whh,   // [1024][256]
    const float* __restrict__ h0a, const float* __restrict__ c0a,
    const float* __restrict__ h0b, const float* __restrict__ c0b,
    float* __restrict__ hx,          // [2 buf][64 grp][2 chain][256]
    float* __restrict__ normAcc,     // [64]
    unsigned* __restrict__ bar,      // [64 * 32] (128B-padded counters)
    float* __restrict__ out)         // [64]
{
    __shared__ __align__(16) float hL[2 * 16 * 20];  // [chain][ks][16+4 pad] (2-way bank = free)
    __shared__ float nrm[64];

    const int tid  = threadIdx.x;
    const int b    = blockIdx.x & 63;
    const int sub  = blockIdx.x >> 6;
    const int ks   = tid & 15;
    const int uL   = tid >> 4;        // 0..63
    const int unit = sub * 64 + uL;   // 0..255

    // Load this thread's weight slice once: rows q*256+unit, cols [ks*16, ks*16+16)
    float4 w[4][4];
#pragma unroll
    for (int q = 0; q < 4; ++q)
#pragma unroll
        for (int i4 = 0; i4 < 4; ++i4)
            w[q][i4] = *(const float4*)(Whh + (size_t)(q * 256 + unit) * 256 + ks * 16 + i4 * 4);

    float cA = 0.f, cB = 0.f;
    if (ks == 0) { cA = c0a[b * 256 + unit]; cB = c0b[b * 256 + unit]; }
    if (tid < 512) {
        const int c = tid >> 8, j = tid & 255;
        const float v = (c == 0 ? h0a : h0b)[b * 256 + j];
        hL[c * 320 + (j >> 4) * 20 + (j & 15)] = v;
    }
    unsigned* mybar = bar + b * 32;
    __syncthreads();

    for (int t = 0; t < TSTEPS; ++t) {
        // gx prefetch (update lanes only) — independent of h, issued before the dot loop.
        float gA[4] = {0, 0, 0, 0}, gB[4] = {0, 0, 0, 0};
        if (ks == 0) {
#pragma unroll
            for (int q = 0; q < 4; ++q) {
                const size_t off = ((size_t)t * 64 + b) * 1024 + q * 256 + unit;
                gA[q] = gx[off];
                gB[q] = gx[(size_t)8192 * 1024 + off];
            }
        }

        float aA[4] = {0, 0, 0, 0}, aB[4] = {0, 0, 0, 0};
#pragma unroll
        for (int i4 = 0; i4 < 4; ++i4) {
            const float* hp = hL + ks * 20 + i4 * 4;
            const float4 ha = *(const float4*)hp;
            const float4 hb = *(const float4*)(hp + 320);
#pragma unroll
            for (int q = 0; q < 4; ++q) {
                aA[q] = fmaf(w[q][i4].x, ha.x, aA[q]);
                aA[q] = fmaf(w[q][i4].y, ha.y, aA[q]);
                aA[q] = fmaf(w[q][i4].z, ha.z, aA[q]);
                aA[q] = fmaf(w[q][i4].w, ha.w, aA[q]);
                aB[q] = fmaf(w[q][i4].x, hb.x, aB[q]);
                aB[q] = fmaf(w[q][i4].y, hb.y, aB[q]);
                aB[q] = fmaf(w[q][i4].z, hb.z, aB[q]);
                aB[q] = fmaf(w[q][i4].w, hb.w, aB[q]);
            }
        }
#pragma unroll
        for (int q = 0; q < 4; ++q) { aA[q] = red16(aA[q]); aB[q] = red16(aB[q]); }

        float hA = 0.f, hB = 0.f;
        if (ks == 0) {
            const float ia = sigmoidf_(aA[0] + gA[0]);
            const float fa = sigmoidf_(aA[1] + gA[1]);
            const float ga = tanhf(aA[2] + gA[2]);
            const float oa = sigmoidf_(aA[3] + gA[3]);
            cA = fmaf(fa, cA, ia * ga);
            hA = oa * tanhf(cA);
            const float ib = sigmoidf_(aB[0] + gB[0]);
            const float fb = sigmoidf_(aB[1] + gB[1]);
            const float gb = tanhf(aB[2] + gB[2]);
            const float ob = sigmoidf_(aB[3] + gB[3]);
            cB = fmaf(fb, cB, ib * gb);
            hB = ob * tanhf(cB);
        }
        __syncthreads();  // all hL reads of step t finished

        if (t < TSTEPS - 1) {
            float* hxb = hx + (size_t)(t & 1) * (64 * 2 * 256);
            if (ks == 0) {
                __hip_atomic_store(&hxb[(b * 2 + 0) * 256 + unit], hA,
                                   __ATOMIC_RELAXED, __HIP_MEMORY_SCOPE_AGENT);
                __hip_atomic_store(&hxb[(b * 2 + 1) * 256 + unit], hB,
                                   __ATOMIC_RELAXED, __HIP_MEMORY_SCOPE_AGENT);
            }
            __syncthreads();  // drains vmem: all 128 h stores at coherence point
            if (tid == 0) {
                __threadfence();
                __hip_atomic_fetch_add(mybar, 1u, __ATOMIC_RELEASE, __HIP_MEMORY_SCOPE_AGENT);
                const unsigned target = 4u * (t + 1);
                while (__hip_atomic_load(mybar, __ATOMIC_ACQUIRE, __HIP_MEMORY_SCOPE_AGENT) < target) {}
            }
            __syncthreads();
            // restage full h (both chains) from exchange buffer
            if (tid < 512) {
                const int c = tid >> 8, j = tid & 255;
                const float v = __hip_atomic_load(&hxb[(b * 2 + c) * 256 + j],
                                                  __ATOMIC_RELAXED, __HIP_MEMORY_SCOPE_AGENT);
                hL[c * 320 + (j >> 4) * 20 + (j & 15)] = v;
            }
            __syncthreads();
        } else {
            if (ks == 0) nrm[uL] = fabsf(hA - hB);
            __syncthreads();
            if (tid == 0) {
                float p = 0.f;
                for (int u = 0; u < 64; ++u) p += nrm[u];
                atomicAdd(&normAcc[b], p);
                __threadfence();
                __hip_atomic_fetch_add(mybar, 1u, __ATOMIC_RELEASE, __HIP_MEMORY_SCOPE_AGENT);
                if (sub == 0) {
                    while (__hip_atomic_load(mybar, __ATOMIC_ACQUIRE, __HIP_MEMORY_SCOPE_AGENT) <
                           4u * TSTEPS) {}
                    const float nv = __hip_atomic_load(&normAcc[b], __ATOMIC_RELAXED,
                                                       __HIP_MEMORY_SCOPE_AGENT);
                    float y = expf(-nv);
                    y = fminf(fmaxf(y, 1e-7f), 1.0f - 1e-7f);
                    out[b] = y;
                }
            }
        }
    }
}

// ---------------------------------------------------------------------------
// Workspace layout (bytes):
//   [0, 64MB)                     gx  : 2*8192*1024 fp32
//   [64MB, +256KB)                hx  : double-buffered h exchange
//   [+0, +4KB)                    normAcc (64 fp32, padded)
//   [+4KB, +12KB)                 bar (64 x 128B counters)
// ---------------------------------------------------------------------------
extern "C" void kernel_launch(void* const* d_in, const int* in_sizes, int n_in,
                              void* d_out, int out_size, void* d_ws, size_t ws_size,
                              hipStream_t stream) {
    const int*   s1  = (const int*)d_in[0];
    const int*   s2  = (const int*)d_in[1];
    const float* emb = (const float*)d_in[2];
    const float* Wih = (const float*)d_in[3];
    const float* Whh = (const float*)d_in[4];
    const float* bih = (const float*)d_in[5];
    const float* bhh = (const float*)d_in[6];
    const float* h0a = (const float*)d_in[7];
    const float* c0a = (const float*)d_in[8];
    const float* h0b = (const float*)d_in[9];
    const float* c0b = (const float*)d_in[10];
    float* out = (float*)d_out;

    char* ws = (char*)d_ws;
    const size_t GX_BYTES  = (size_t)2 * 8192 * 1024 * 4;   // 64 MB
    const size_t HX_BYTES  = (size_t)2 * 64 * 2 * 256 * 4;  // 256 KB
    float*    gx      = (float*)ws;
    float*    hx      = (float*)(ws + GX_BYTES);
    float*    normAcc = (float*)(ws + GX_BYTES + HX_BYTES);
    unsigned* bar     = (unsigned*)(ws + GX_BYTES + HX_BYTES + 4096);

    // zero counters + norm accumulators (ws is re-poisoned to 0xAA before every call)
    hipMemsetAsync(ws + GX_BYTES + HX_BYTES, 0, 12288, stream);

    gx_gemm_kernel<<<2048, 256, 0, stream>>>(s1, s2, emb, Wih, bih, bhh, gx);

    lstm_rec_kernel<<<256, 1024, 0, stream>>>(gx, Whh, h0a, c0a, h0b, c0b,
                                              hx, normAcc, bar, out);
}

// Round 3
// 539.227 us; speedup vs baseline: 3.6438x; 3.6438x over previous
//
#include <hip/hip_runtime.h>
#include <hip/hip_fp16.h>
#include <math.h>

// dims: T=128, B=64, V=100000, D=300, H=256
#define TSTEPS 128

typedef __attribute__((ext_vector_type(2))) _Float16 half2v;

#if __has_builtin(__builtin_amdgcn_fdot2)
#define FDOT2(a, b, c) __builtin_amdgcn_fdot2((a), (b), (c), false)
#else
static __device__ __forceinline__ float FDOT2(half2v a, half2v b, float c) {
    return c + (float)a.x * (float)b.x + (float)a.y * (float)b.y;
}
#endif

static __device__ __forceinline__ half2v h2(unsigned u) {
    union { unsigned x; half2v h; } t; t.x = u; return t.h;
}
static __device__ __forceinline__ unsigned packh2(float lo, float hi) {
    union { unsigned x; half2v h; } t; t.h.x = (_Float16)lo; t.h.y = (_Float16)hi; return t.x;
}
static __device__ __forceinline__ float sigm(float x) { return 1.0f / (1.0f + __expf(-x)); }
static __device__ __forceinline__ float tanh_(float x) { return 1.0f - 2.0f / (1.0f + __expf(2.0f * x)); }

// ---------------------------------------------------------------------------
// Kernel 0: W_hh fp32[1024][256] -> W16T uint[128][1024], W16T[i][r] = half2(W[r][2i], W[r][2i+1])
// 32 blocks x 256 threads, 32 rows per block.
// ---------------------------------------------------------------------------
__global__ __launch_bounds__(256) void prep_whh(const float* __restrict__ Whh,
                                                unsigned* __restrict__ W16T) {
    __shared__ float tile[32][259];
    const int blk = blockIdx.x, tid = threadIdx.x;
#pragma unroll
    for (int l = 0; l < 32; ++l) {
        int idx = tid + l * 256;            // 32*256 = 8192 floats
        int r = idx >> 8, k = idx & 255;
        tile[r][k] = Whh[(size_t)(blk * 32 + r) * 256 + k];
    }
    __syncthreads();
#pragma unroll
    for (int l = 0; l < 16; ++l) {
        int o = tid + l * 256;              // 128 i * 32 rl = 4096
        int i = o >> 5, rl = o & 31;
        W16T[(size_t)i * 1024 + blk * 32 + rl] = packh2(tile[rl][2 * i], tile[rl][2 * i + 1]);
    }
}

// ---------------------------------------------------------------------------
// Kernel 1: gx[m][n] = emb[tok(m)] . W_ih[n] + b_ih[n] + b_hh[n]
// M=16384 (seq-major), N=1024, K=300. Tile 128x128, BK=60, 256 thr, 8x8 micro.
// XOR-swizzled LDS (k-dependent) -> conflict-light staging + conflict-free reads.
// ---------------------------------------------------------------------------
__global__ __launch_bounds__(256, 2) void gx_gemm(
    const int* __restrict__ s1, const int* __restrict__ s2,
    const float* __restrict__ emb, const float* __restrict__ Wih,
    const float* __restrict__ bih, const float* __restrict__ bhh,
    float* __restrict__ gx)
{
    __shared__ __align__(16) float As[60 * 132];
    __shared__ __align__(16) float Bs[60 * 132];
    __shared__ int tokS[128];

    const int tid = threadIdx.x;
    const int bm = blockIdx.x & 127, bn = blockIdx.x >> 7;
    const int m0 = bm * 128, n0 = bn * 128;
    const int* __restrict__ s = (m0 < 8192) ? s1 : s2;
    const int r0 = m0 & 8191;
    if (tid < 128) tokS[tid] = s[r0 + tid];

    const int tx = tid & 15, ty = tid >> 4;
    float acc[8][8] = {};
    __syncthreads();

    for (int kk = 0; kk < 5; ++kk) {
        const int k0 = kk * 60;
#pragma unroll
        for (int l = 0; l < 8; ++l) {
            int f4 = tid + l * 256;
            if (f4 < 1920) {
                int m = f4 / 15, j = f4 - m * 15;
                float4 v = *(const float4*)(emb + (size_t)tokS[m] * 300 + k0 + j * 4);
                int kb = j * 4;
                As[(kb + 0) * 132 + (m ^ (((kb + 0) & 7) << 2))] = v.x;
                As[(kb + 1) * 132 + (m ^ (((kb + 1) & 7) << 2))] = v.y;
                As[(kb + 2) * 132 + (m ^ (((kb + 2) & 7) << 2))] = v.z;
                As[(kb + 3) * 132 + (m ^ (((kb + 3) & 7) << 2))] = v.w;
            }
        }
#pragma unroll
        for (int l = 0; l < 8; ++l) {
            int f4 = tid + l * 256;
            if (f4 < 1920) {
                int n = f4 / 15, j = f4 - n * 15;
                float4 v = *(const float4*)(Wih + (size_t)(n0 + n) * 300 + k0 + j * 4);
                int kb = j * 4;
                Bs[(kb + 0) * 132 + (n ^ (((kb + 0) & 7) << 2))] = v.x;
                Bs[(kb + 1) * 132 + (n ^ (((kb + 1) & 7) << 2))] = v.y;
                Bs[(kb + 2) * 132 + (n ^ (((kb + 2) & 7) << 2))] = v.z;
                Bs[(kb + 3) * 132 + (n ^ (((kb + 3) & 7) << 2))] = v.w;
            }
        }
        __syncthreads();

#pragma unroll 6
        for (int k = 0; k < 60; ++k) {
            const int sw = (k & 7) << 2;
            const float4 a0 = *(const float4*)&As[k * 132 + ((ty * 4) ^ sw)];
            const float4 a1 = *(const float4*)&As[k * 132 + (64 + ((ty * 4) ^ sw))];
            const float4 b0 = *(const float4*)&Bs[k * 132 + ((tx * 4) ^ sw)];
            const float4 b1 = *(const float4*)&Bs[k * 132 + (64 + ((tx * 4) ^ sw))];
            const float av[8] = {a0.x, a0.y, a0.z, a0.w, a1.x, a1.y, a1.z, a1.w};
            const float bv[8] = {b0.x, b0.y, b0.z, b0.w, b1.x, b1.y, b1.z, b1.w};
#pragma unroll
            for (int i = 0; i < 8; ++i)
#pragma unroll
                for (int j = 0; j < 8; ++j)
                    acc[i][j] = fmaf(av[i], bv[j], acc[i][j]);
        }
        __syncthreads();
    }

    float bs[8];
    {
        const float4 xa = *(const float4*)(bih + n0 + tx * 4);
        const float4 xb = *(const float4*)(bhh + n0 + tx * 4);
        const float4 ya = *(const float4*)(bih + n0 + 64 + tx * 4);
        const float4 yb = *(const float4*)(bhh + n0 + 64 + tx * 4);
        bs[0] = xa.x + xb.x; bs[1] = xa.y + xb.y; bs[2] = xa.z + xb.z; bs[3] = xa.w + xb.w;
        bs[4] = ya.x + yb.x; bs[5] = ya.y + yb.y; bs[6] = ya.z + yb.z; bs[7] = ya.w + yb.w;
    }
#pragma unroll
    for (int i = 0; i < 8; ++i) {
        const int m = m0 + ((i < 4) ? (ty * 4 + i) : (64 + ty * 4 + i - 4));
        float4 lo = make_float4(acc[i][0] + bs[0], acc[i][1] + bs[1], acc[i][2] + bs[2], acc[i][3] + bs[3]);
        float4 hi = make_float4(acc[i][4] + bs[4], acc[i][5] + bs[5], acc[i][6] + bs[6], acc[i][7] + bs[7]);
        *(float4*)(gx + (size_t)m * 1024 + n0 + tx * 4) = lo;
        *(float4*)(gx + (size_t)m * 1024 + n0 + 64 + tx * 4) = hi;
    }
}

// ---------------------------------------------------------------------------
// Kernel 2: recurrence. 128 blocks (one per chain) x 512 threads. NO cross-CU sync.
// Full W_hh fp16-resident per CU: 96 k-pairs/row in VGPRs (192 regs/thread),
// 32 k-pairs/row in LDS (per-thread 68-dword padded blocks, conflict-free b128).
// Thread (u = tid&255, p = tid>>8): rows r0 = p*512+u (i|g), r1 = r0+256 (f|o).
// ---------------------------------------------------------------------------
__global__ __launch_bounds__(512) void lstm_rec(
    const unsigned* __restrict__ W16T,   // [128][1024]
    const float* __restrict__ gx,        // [16384][1024]
    const float* __restrict__ h0a, const float* __restrict__ c0a,
    const float* __restrict__ h0b, const float* __restrict__ c0b,
    float* __restrict__ hfin)            // [128][256]
{
    extern __shared__ unsigned smem[];
    unsigned* wlds = smem;                         // 512*68 dwords
    unsigned* hbuf = smem + 512 * 68;              // 128 dwords (h as half2)
    float*    pre  = (float*)(smem + 512 * 68 + 128); // 512 floats (g, o pre-acts)

    const int tid = threadIdx.x;
    const int chain = blockIdx.x;                  // seq = chain>>6, b = chain&63
    const int u = tid & 255, p = tid >> 8;
    const int r0 = (p << 9) + u;
    const int r1 = r0 + 256;

    // VGPR-resident weights: k-pairs 0..95 of both rows
    unsigned w0[96], w1[96];
#pragma unroll
    for (int i = 0; i < 96; ++i) w0[i] = W16T[(size_t)i * 1024 + r0];
#pragma unroll
    for (int i = 0; i < 96; ++i) w1[i] = W16T[(size_t)i * 1024 + r1];
#pragma unroll
    for (int i = 0; i < 96; ++i) {
        asm volatile("" : "+v"(w0[i]));
        asm volatile("" : "+v"(w1[i]));
    }
    // LDS weights: k-pairs 96..127 -> per-thread block of 64 dwords (stride 68)
    {
        unsigned* mb = wlds + tid * 68;
#pragma unroll
        for (int j = 0; j < 32; ++j) mb[j] = W16T[(size_t)(96 + j) * 1024 + r0];
#pragma unroll
        for (int j = 0; j < 32; ++j) mb[32 + j] = W16T[(size_t)(96 + j) * 1024 + r1];
    }

    float c_state = 0.f;
    if (p == 0) {
        const float* c0 = (chain & 64) ? c0b : c0a;
        const float* h0 = (chain & 64) ? h0b : h0a;
        c_state = c0[(chain & 63) * 256 + u];
        ((_Float16*)hbuf)[u] = (_Float16)h0[(chain & 63) * 256 + u];
    }
    __syncthreads();

    const float* gxb = gx + ((size_t)(chain >> 6) * 8192 + (size_t)(chain & 63)) * 1024;
    const unsigned* mb = wlds + tid * 68;

    for (int t = 0; t < TSTEPS; ++t) {
        const float gxv0 = gxb[(size_t)t * 65536 + r0];   // issued early, used ~1000cyc later
        const float gxv1 = gxb[(size_t)t * 65536 + r1];

        float acc0 = 0.f, acc1 = 0.f;
#pragma unroll
        for (int cc = 0; cc < 24; ++cc) {                 // k-pairs 0..95 (VGPR weights)
            const uint4 hv = *(const uint4*)&hbuf[cc * 4];
            acc0 = FDOT2(h2(w0[cc * 4 + 0]), h2(hv.x), acc0);
            acc1 = FDOT2(h2(w1[cc * 4 + 0]), h2(hv.x), acc1);
            acc0 = FDOT2(h2(w0[cc * 4 + 1]), h2(hv.y), acc0);
            acc1 = FDOT2(h2(w1[cc * 4 + 1]), h2(hv.y), acc1);
            acc0 = FDOT2(h2(w0[cc * 4 + 2]), h2(hv.z), acc0);
            acc1 = FDOT2(h2(w1[cc * 4 + 2]), h2(hv.z), acc1);
            acc0 = FDOT2(h2(w0[cc * 4 + 3]), h2(hv.w), acc0);
            acc1 = FDOT2(h2(w1[cc * 4 + 3]), h2(hv.w), acc1);
        }
#pragma unroll
        for (int cc = 0; cc < 4; ++cc) {                  // k-pairs 96..127 (LDS weights)
            const uint4 hv0 = *(const uint4*)&hbuf[96 + cc * 8];
            const uint4 hv1 = *(const uint4*)&hbuf[96 + cc * 8 + 4];
            const uint4 wa = *(const uint4*)&mb[cc * 8];
            const uint4 wb = *(const uint4*)&mb[cc * 8 + 4];
            const uint4 wc = *(const uint4*)&mb[32 + cc * 8];
            const uint4 wd = *(const uint4*)&mb[32 + cc * 8 + 4];
            acc0 = FDOT2(h2(wa.x), h2(hv0.x), acc0);  acc1 = FDOT2(h2(wc.x), h2(hv0.x), acc1);
            acc0 = FDOT2(h2(wa.y), h2(hv0.y), acc0);  acc1 = FDOT2(h2(wc.y), h2(hv0.y), acc1);
            acc0 = FDOT2(h2(wa.z), h2(hv0.z), acc0);  acc1 = FDOT2(h2(wc.z), h2(hv0.z), acc1);
            acc0 = FDOT2(h2(wa.w), h2(hv0.w), acc0);  acc1 = FDOT2(h2(wc.w), h2(hv0.w), acc1);
            acc0 = FDOT2(h2(wb.x), h2(hv1.x), acc0);  acc1 = FDOT2(h2(wd.x), h2(hv1.x), acc1);
            acc0 = FDOT2(h2(wb.y), h2(hv1.y), acc0);  acc1 = FDOT2(h2(wd.y), h2(hv1.y), acc1);
            acc0 = FDOT2(h2(wb.z), h2(hv1.z), acc0);  acc1 = FDOT2(h2(wd.z), h2(hv1.z), acc1);
            acc0 = FDOT2(h2(wb.w), h2(hv1.w), acc0);  acc1 = FDOT2(h2(wd.w), h2(hv1.w), acc1);
        }
        acc0 += gxv0;
        acc1 += gxv1;

        if (p) { pre[u] = acc0; pre[256 + u] = acc1; }    // g, o pre-activations
        __syncthreads();                                  // pre visible; all hbuf reads done
        if (!p) {
            const float gi = sigm(acc0);
            const float gf = sigm(acc1);
            const float gg = tanh_(pre[u]);
            const float go = sigm(pre[256 + u]);
            c_state = fmaf(gf, c_state, gi * gg);
            const float h = go * tanh_(c_state);
            ((_Float16*)hbuf)[u] = (_Float16)h;
            if (t == TSTEPS - 1) hfin[(size_t)chain * 256 + u] = h;
        }
        __syncthreads();
    }
}

// ---------------------------------------------------------------------------
// Kernel 3: y[b] = clip(exp(-sum_u |hA[b][u] - hB[b][u]|)). 64 blocks x 256 thr.
// ---------------------------------------------------------------------------
__global__ __launch_bounds__(256) void final_norm(const float* __restrict__ hfin,
                                                  float* __restrict__ out) {
    __shared__ float ws[4];
    const int b = blockIdx.x, tid = threadIdx.x;
    float d = fabsf(hfin[(size_t)b * 256 + tid] - hfin[(size_t)(64 + b) * 256 + tid]);
#pragma unroll
    for (int off = 32; off; off >>= 1) d += __shfl_down(d, off);
    if ((tid & 63) == 0) ws[tid >> 6] = d;
    __syncthreads();
    if (tid == 0) {
        float n = ws[0] + ws[1] + ws[2] + ws[3];
        float y = expf(-n);
        y = fminf(fmaxf(y, 1e-7f), 1.0f - 1e-7f);
        out[b] = y;
    }
}

// ---------------------------------------------------------------------------
// Workspace: [0,64MB) gx | [64MB,+512KB) W16T | [+512KB,+128KB) hfin
// ---------------------------------------------------------------------------
extern "C" void kernel_launch(void* const* d_in, const int* in_sizes, int n_in,
                              void* d_out, int out_size, void* d_ws, size_t ws_size,
                              hipStream_t stream) {
    const int*   s1  = (const int*)d_in[0];
    const int*   s2  = (const int*)d_in[1];
    const float* emb = (const float*)d_in[2];
    const float* Wih = (const float*)d_in[3];
    const float* Whh = (const float*)d_in[4];
    const float* bih = (const float*)d_in[5];
    const float* bhh = (const float*)d_in[6];
    const float* h0a = (const float*)d_in[7];
    const float* c0a = (const float*)d_in[8];
    const float* h0b = (const float*)d_in[9];
    const float* c0b = (const float*)d_in[10];
    float* out = (float*)d_out;

    char* ws = (char*)d_ws;
    const size_t GX_BYTES = (size_t)16384 * 1024 * 4;        // 64 MB
    float*    gx   = (float*)ws;
    unsigned* W16T = (unsigned*)(ws + GX_BYTES);             // 512 KB
    float*    hfin = (float*)(ws + GX_BYTES + (size_t)512 * 1024);  // 128 KB

    prep_whh<<<32, 256, 0, stream>>>(Whh, W16T);
    gx_gemm<<<1024, 256, 0, stream>>>(s1, s2, emb, Wih, bih, bhh, gx);

    const int rec_lds = (512 * 68 + 128 + 512) * 4;          // 141824 B dynamic LDS
    lstm_rec<<<128, 512, rec_lds, stream>>>(W16T, gx, h0a, c0a, h0b, c0b, hfin);

    final_norm<<<64, 256, 0, stream>>>(hfin, out);
}

// Round 4
// 418.972 us; speedup vs baseline: 4.6896x; 1.2870x over previous
//
#include <hip/hip_runtime.h>
#include <hip/hip_fp16.h>
#include <math.h>

// dims: T=128, B=64, V=100000, D=300, H=256
#define TSTEPS 128

typedef _Float16 half8 __attribute__((ext_vector_type(8)));
typedef float f32x4 __attribute__((ext_vector_type(4)));
typedef __attribute__((ext_vector_type(2))) _Float16 half2v;

#if __has_builtin(__builtin_amdgcn_fdot2)
#define FDOT2(a, b, c) __builtin_amdgcn_fdot2((a), (b), (c), false)
#else
static __device__ __forceinline__ float FDOT2(half2v a, half2v b, float c) {
    return c + (float)a.x * (float)b.x + (float)a.y * (float)b.y;
}
#endif

static __device__ __forceinline__ half2v h2(unsigned u) {
    union { unsigned x; half2v h; } t; t.x = u; return t.h;
}
static __device__ __forceinline__ unsigned packh2(float lo, float hi) {
    union { unsigned x; half2v h; } t; t.h.x = (_Float16)lo; t.h.y = (_Float16)hi; return t.x;
}
static __device__ __forceinline__ float sigm(float x) { return 1.0f / (1.0f + __expf(-x)); }
static __device__ __forceinline__ float tanh_(float x) { return 1.0f - 2.0f / (1.0f + __expf(2.0f * x)); }

typedef __attribute__((address_space(1))) const unsigned GU;
typedef __attribute__((address_space(3))) unsigned LU;
static __device__ __forceinline__ void glds16(const void* g, void* l) {
    __builtin_amdgcn_global_load_lds((GU*)g, (LU*)(uintptr_t)l, 16, 0, 0);
}

// ---------------------------------------------------------------------------
// Kernel A: W_hh fp32[1024][256] -> W16T uint[128][1024] (half2-packed, k-pair major)
// ---------------------------------------------------------------------------
__global__ __launch_bounds__(256) void prep_whh(const float* __restrict__ Whh,
                                                unsigned* __restrict__ W16T) {
    __shared__ float tile[32][259];
    const int blk = blockIdx.x, tid = threadIdx.x;
#pragma unroll
    for (int l = 0; l < 32; ++l) {
        int idx = tid + l * 256;
        int r = idx >> 8, k = idx & 255;
        tile[r][k] = Whh[(size_t)(blk * 32 + r) * 256 + k];
    }
    __syncthreads();
#pragma unroll
    for (int l = 0; l < 16; ++l) {
        int o = tid + l * 256;
        int i = o >> 5, rl = o & 31;
        W16T[(size_t)i * 1024 + blk * 32 + rl] = packh2(tile[rl][2 * i], tile[rl][2 * i + 1]);
    }
}

// ---------------------------------------------------------------------------
// Fragment-major fp16 layouts for mfma_f32_16x16x32_f16.
// Granule G = (fr*10 + ks)*64 + lane holds 8 halfs for MFMA lane `lane`:
//   row = fr*16 + (lane&15); k = ks*32 + (lane>>4)*4 + {0..3} and +{16..19}.
// ---------------------------------------------------------------------------
__global__ __launch_bounds__(256) void gather_x(
    const int* __restrict__ s1, const int* __restrict__ s2,
    const float* __restrict__ emb, _Float16* __restrict__ xf)   // 655360 granules
{
    const int G = blockIdx.x * 256 + threadIdx.x;
    const int lane = G & 63;
    const int tmp = G >> 6;
    const int ks = tmp % 10;
    const int fr = tmp / 10;                    // 0..1023
    const int m = fr * 16 + (lane & 15);
    const int tok = (m < 8192) ? s1[m] : s2[m - 8192];
    const float* row = emb + (size_t)tok * 300;
    const int k0 = ks * 32 + ((lane >> 4) & 3) * 4;
    half8 o;
#pragma unroll
    for (int c = 0; c < 2; ++c) {
        const int kc = k0 + c * 16;
#pragma unroll
        for (int j = 0; j < 4; ++j)
            o[c * 4 + j] = (_Float16)((kc + j < 300) ? row[kc + j] : 0.f);
    }
    *(half8*)(xf + (size_t)G * 8) = o;
}

__global__ __launch_bounds__(256) void gather_w(
    const float* __restrict__ Wih, _Float16* __restrict__ wf)   // 40960 granules
{
    const int G = blockIdx.x * 256 + threadIdx.x;
    const int lane = G & 63;
    const int tmp = G >> 6;
    const int ks = tmp % 10;
    const int fr = tmp / 10;                    // 0..63
    const int n = fr * 16 + (lane & 15);
    const float* row = Wih + (size_t)n * 300;
    const int k0 = ks * 32 + ((lane >> 4) & 3) * 4;
    half8 o;
#pragma unroll
    for (int c = 0; c < 2; ++c) {
        const int kc = k0 + c * 16;
#pragma unroll
        for (int j = 0; j < 4; ++j)
            o[c * 4 + j] = (_Float16)((kc + j < 300) ? row[kc + j] : 0.f);
    }
    *(half8*)(wf + (size_t)G * 8) = o;
}

// ---------------------------------------------------------------------------
// Kernel B: gx16 = x @ Wih^T (NO bias), fp16 in/out, fp32 MFMA accumulate.
// M=16384, N=1024, K=320 (zero-padded). 128x128 tile, 256 thr (4 waves 2x2),
// double-buffered LDS via global_load_lds (linear, frag-major => conflict-free).
// ---------------------------------------------------------------------------
__global__ __launch_bounds__(256) void gx_gemm_mfma(
    const _Float16* __restrict__ xf, const _Float16* __restrict__ wf,
    _Float16* __restrict__ gx16)
{
    __shared__ _Float16 sm[2][8192];            // [buf][A:4096 | B:4096] halfs = 32 KB
    const int tid = threadIdx.x;
    const int lane = tid & 63, wv = tid >> 6;
    const int wr = wv >> 1, wc = wv & 1;
    const int bm = blockIdx.x & 127, bn = blockIdx.x >> 7;
    const int frM = bm * 8, frN = bn * 8;

    f32x4 acc[4][4] = {};

#define STAGE(buf, ks)                                                              \
    {                                                                               \
        _Pragma("unroll")                                                           \
        for (int i_ = 0; i_ < 2; ++i_) {                                            \
            const int fr_ = wv + 4 * i_;                                            \
            glds16(xf + (((size_t)(frM + fr_) * 10 + (ks)) * 64 + lane) * 8,        \
                   &sm[buf][fr_ * 512 + lane * 8]);                                 \
            glds16(wf + (((size_t)(frN + fr_) * 10 + (ks)) * 64 + lane) * 8,        \
                   &sm[buf][4096 + fr_ * 512 + lane * 8]);                          \
        }                                                                           \
    }

    STAGE(0, 0)
    for (int ks = 0; ks < 10; ++ks) {
        const int cur = ks & 1;
        if (ks < 9) {
            STAGE(cur ^ 1, ks + 1)
            asm volatile("s_waitcnt vmcnt(4)" ::: "memory");   // cur's 4 loads landed
        } else {
            asm volatile("s_waitcnt vmcnt(0)" ::: "memory");
        }
        __syncthreads();
        half8 av[4], bv[4];
#pragma unroll
        for (int i = 0; i < 4; ++i) {
            av[i] = *(const half8*)&sm[cur][(wr * 4 + i) * 512 + lane * 8];
            bv[i] = *(const half8*)&sm[cur][4096 + (wc * 4 + i) * 512 + lane * 8];
        }
#pragma unroll
        for (int i = 0; i < 4; ++i)
#pragma unroll
            for (int j = 0; j < 4; ++j)
                acc[i][j] = __builtin_amdgcn_mfma_f32_16x16x32_f16(av[i], bv[j], acc[i][j], 0, 0, 0);
        __syncthreads();
    }
#undef STAGE

    const int m0 = bm * 128 + wr * 64, n0 = bn * 128 + wc * 64;
    const int rl = ((lane >> 4) & 3) * 4, cl = lane & 15;
#pragma unroll
    for (int i = 0; i < 4; ++i)
#pragma unroll
        for (int j = 0; j < 4; ++j)
#pragma unroll
            for (int r = 0; r < 4; ++r)
                gx16[(size_t)(m0 + i * 16 + rl + r) * 1024 + n0 + j * 16 + cl] =
                    (_Float16)acc[i][j][r];
}

// ---------------------------------------------------------------------------
// Kernel C: recurrence. 128 blocks (one per chain) x 512 threads, no cross-CU sync.
// Weights fp16: 96 k-pairs/row x 2 rows in regs, 32 k-pairs in LDS. Biases fp32 here.
// ---------------------------------------------------------------------------
__global__ __launch_bounds__(512) void lstm_rec(
    const unsigned* __restrict__ W16T,   // [128][1024]
    const unsigned short* __restrict__ gx16,  // [16384][1024] fp16 bits
    const float* __restrict__ bih, const float* __restrict__ bhh,
    const float* __restrict__ h0a, const float* __restrict__ c0a,
    const float* __restrict__ h0b, const float* __restrict__ c0b,
    float* __restrict__ hfin)            // [128][256]
{
    extern __shared__ unsigned smem[];
    unsigned* wlds = smem;                            // 512*68 dwords
    unsigned* hbuf = smem + 512 * 68;                 // 128 dwords (h as half2)
    float*    pre  = (float*)(smem + 512 * 68 + 128); // 512 floats

    const int tid = threadIdx.x;
    const int chain = blockIdx.x;
    const int u = tid & 255, p = tid >> 8;
    const int r0 = (p << 9) + u;          // p=0: i-row u     | p=1: g-row 512+u
    const int r1 = r0 + 256;              // p=0: f-row 256+u | p=1: o-row 768+u

    const float bias0 = bih[r0] + bhh[r0];
    const float bias1 = bih[r1] + bhh[r1];

    unsigned w0[96], w1[96];
#pragma unroll
    for (int i = 0; i < 96; ++i) w0[i] = W16T[(size_t)i * 1024 + r0];
#pragma unroll
    for (int i = 0; i < 96; ++i) w1[i] = W16T[(size_t)i * 1024 + r1];
#pragma unroll
    for (int i = 0; i < 96; ++i) {
        asm volatile("" : "+v"(w0[i]));
        asm volatile("" : "+v"(w1[i]));
    }
    {
        unsigned* mb = wlds + tid * 68;
#pragma unroll
        for (int j = 0; j < 32; ++j) mb[j] = W16T[(size_t)(96 + j) * 1024 + r0];
#pragma unroll
        for (int j = 0; j < 32; ++j) mb[32 + j] = W16T[(size_t)(96 + j) * 1024 + r1];
    }

    float c_state = 0.f;
    if (p == 0) {
        const float* c0 = (chain & 64) ? c0b : c0a;
        const float* h0 = (chain & 64) ? h0b : h0a;
        c_state = c0[(chain & 63) * 256 + u];
        ((_Float16*)hbuf)[u] = (_Float16)h0[(chain & 63) * 256 + u];
    }
    __syncthreads();

    const unsigned short* gxb = gx16 + ((size_t)(chain >> 6) * 8192 + (size_t)(chain & 63)) * 1024;
    const unsigned* mb = wlds + tid * 68;

    for (int t = 0; t < TSTEPS; ++t) {
        const unsigned short gr0 = gxb[(size_t)t * 65536 + r0];   // early issue
        const unsigned short gr1 = gxb[(size_t)t * 65536 + r1];

        float acc0 = 0.f, acc1 = 0.f;
#pragma unroll
        for (int cc = 0; cc < 24; ++cc) {
            const uint4 hv = *(const uint4*)&hbuf[cc * 4];
            acc0 = FDOT2(h2(w0[cc * 4 + 0]), h2(hv.x), acc0);
            acc1 = FDOT2(h2(w1[cc * 4 + 0]), h2(hv.x), acc1);
            acc0 = FDOT2(h2(w0[cc * 4 + 1]), h2(hv.y), acc0);
            acc1 = FDOT2(h2(w1[cc * 4 + 1]), h2(hv.y), acc1);
            acc0 = FDOT2(h2(w0[cc * 4 + 2]), h2(hv.z), acc0);
            acc1 = FDOT2(h2(w1[cc * 4 + 2]), h2(hv.z), acc1);
            acc0 = FDOT2(h2(w0[cc * 4 + 3]), h2(hv.w), acc0);
            acc1 = FDOT2(h2(w1[cc * 4 + 3]), h2(hv.w), acc1);
        }
#pragma unroll
        for (int cc = 0; cc < 4; ++cc) {
            const uint4 hv0 = *(const uint4*)&hbuf[96 + cc * 8];
            const uint4 hv1 = *(const uint4*)&hbuf[96 + cc * 8 + 4];
            const uint4 wa = *(const uint4*)&mb[cc * 8];
            const uint4 wb = *(const uint4*)&mb[cc * 8 + 4];
            const uint4 wc = *(const uint4*)&mb[32 + cc * 8];
            const uint4 wd = *(const uint4*)&mb[32 + cc * 8 + 4];
            acc0 = FDOT2(h2(wa.x), h2(hv0.x), acc0);  acc1 = FDOT2(h2(wc.x), h2(hv0.x), acc1);
            acc0 = FDOT2(h2(wa.y), h2(hv0.y), acc0);  acc1 = FDOT2(h2(wc.y), h2(hv0.y), acc1);
            acc0 = FDOT2(h2(wa.z), h2(hv0.z), acc0);  acc1 = FDOT2(h2(wc.z), h2(hv0.z), acc1);
            acc0 = FDOT2(h2(wa.w), h2(hv0.w), acc0);  acc1 = FDOT2(h2(wc.w), h2(hv0.w), acc1);
            acc0 = FDOT2(h2(wb.x), h2(hv1.x), acc0);  acc1 = FDOT2(h2(wd.x), h2(hv1.x), acc1);
            acc0 = FDOT2(h2(wb.y), h2(hv1.y), acc0);  acc1 = FDOT2(h2(wd.y), h2(hv1.y), acc1);
            acc0 = FDOT2(h2(wb.z), h2(hv1.z), acc0);  acc1 = FDOT2(h2(wd.z), h2(hv1.z), acc1);
            acc0 = FDOT2(h2(wb.w), h2(hv1.w), acc0);  acc1 = FDOT2(h2(wd.w), h2(hv1.w), acc1);
        }
        acc0 += (float)*(const _Float16*)&gr0 + bias0;
        acc1 += (float)*(const _Float16*)&gr1 + bias1;

        float gi = 0.f, gf = 0.f;
        if (p) {                                  // pre-activate g,o off the critical path
            pre[u] = tanh_(acc0);
            pre[256 + u] = sigm(acc1);
        } else {                                  // i,f activations before the barrier too
            gi = sigm(acc0);
            gf = sigm(acc1);
        }
        __syncthreads();                          // pre visible; all hbuf reads done
        if (!p) {
            c_state = fmaf(gf, c_state, gi * pre[u]);
            const float h = pre[256 + u] * tanh_(c_state);
            ((_Float16*)hbuf)[u] = (_Float16)h;
            if (t == TSTEPS - 1) hfin[(size_t)chain * 256 + u] = h;
        }
        __syncthreads();
    }
}

// ---------------------------------------------------------------------------
// Kernel D: y[b] = clip(exp(-sum_u |hA - hB|))
// ---------------------------------------------------------------------------
__global__ __launch_bounds__(256) void final_norm(const float* __restrict__ hfin,
                                                  float* __restrict__ out) {
    __shared__ float ws[4];
    const int b = blockIdx.x, tid = threadIdx.x;
    float d = fabsf(hfin[(size_t)b * 256 + tid] - hfin[(size_t)(64 + b) * 256 + tid]);
#pragma unroll
    for (int off = 32; off; off >>= 1) d += __shfl_down(d, off);
    if ((tid & 63) == 0) ws[tid >> 6] = d;
    __syncthreads();
    if (tid == 0) {
        float n = ws[0] + ws[1] + ws[2] + ws[3];
        float y = expf(-n);
        y = fminf(fmaxf(y, 1e-7f), 1.0f - 1e-7f);
        out[b] = y;
    }
}

// ---------------------------------------------------------------------------
// Workspace:
//   xf    @ 0         : 16384*320 fp16 frag-major   (10,485,760 B)
//   wf    @ 10485760  : 1024*320 fp16 frag-major    (655,360 B)
//   gx16  @ 16 MB     : 16384*1024 fp16             (33,554,432 B)
//   W16T  @ 50331648  : 512 KB
//   hfin  @ 50855936  : 128 KB
// ---------------------------------------------------------------------------
extern "C" void kernel_launch(void* const* d_in, const int* in_sizes, int n_in,
                              void* d_out, int out_size, void* d_ws, size_t ws_size,
                              hipStream_t stream) {
    const int*   s1  = (const int*)d_in[0];
    const int*   s2  = (const int*)d_in[1];
    const float* emb = (const float*)d_in[2];
    const float* Wih = (const float*)d_in[3];
    const float* Whh = (const float*)d_in[4];
    const float* bih = (const float*)d_in[5];
    const float* bhh = (const float*)d_in[6];
    const float* h0a = (const float*)d_in[7];
    const float* c0a = (const float*)d_in[8];
    const float* h0b = (const float*)d_in[9];
    const float* c0b = (const float*)d_in[10];
    float* out = (float*)d_out;

    char* ws = (char*)d_ws;
    _Float16* xf   = (_Float16*)ws;
    _Float16* wfp  = (_Float16*)(ws + 10485760);
    _Float16* gx16 = (_Float16*)(ws + (size_t)16 * 1024 * 1024);
    unsigned* W16T = (unsigned*)(ws + 50331648);
    float*    hfin = (float*)(ws + 50855936);

    prep_whh<<<32, 256, 0, stream>>>(Whh, W16T);
    gather_x<<<2560, 256, 0, stream>>>(s1, s2, emb, xf);
    gather_w<<<160, 256, 0, stream>>>(Wih, wfp);
    gx_gemm_mfma<<<1024, 256, 0, stream>>>(xf, wfp, gx16);

    const int rec_lds = (512 * 68 + 128 + 512) * 4;   // 141,824 B
    lstm_rec<<<128, 512, rec_lds, stream>>>(W16T, (const unsigned short*)gx16,
                                            bih, bhh, h0a, c0a, h0b, c0b, hfin);
    final_norm<<<64, 256, 0, stream>>>(hfin, out);
}